// Round 2
// baseline (377.544 us; speedup 1.0000x reference)
//
#include <hip/hip_runtime.h>
#include <hip/hip_bf16.h>
#include <stdint.h>

typedef unsigned short u16;
typedef __attribute__((ext_vector_type(8))) short bf16x8;
typedef __attribute__((ext_vector_type(4))) short bf16x4;
typedef __attribute__((ext_vector_type(4))) float f32x4;
typedef __attribute__((ext_vector_type(4))) unsigned short u16x4;

__device__ __forceinline__ float bf2f(u16 u) {
  union { unsigned i; float f; } c; c.i = ((unsigned)u) << 16; return c.f;
}
__device__ __forceinline__ u16 f2bf(float f) {
  union { float f; unsigned i; } c; c.f = f;
  unsigned r = c.i + 0x7FFFu + ((c.i >> 16) & 1u);
  return (u16)(r >> 16);
}
// async global->LDS, 16B per lane; LDS dest is wave-uniform base + lane*16
__device__ __forceinline__ void gl2lds16(const u16* g, u16* l) {
  __builtin_amdgcn_global_load_lds(
      (const __attribute__((address_space(1))) unsigned int*)(uintptr_t)g,
      (__attribute__((address_space(3))) unsigned int*)(uintptr_t)l,
      16, 0, 0);
}

// ---------------- K0: convert weights to bf16 ----------------
// WT[tap][o][c] from wo[o][c][ky][kx]; WQKV[sel][o][c] from wq/wk/wv.
__global__ void k_prep(const float* __restrict__ wo, const float* __restrict__ wq,
                       const float* __restrict__ wk, const float* __restrict__ wv,
                       u16* __restrict__ WT, u16* __restrict__ WQKV) {
  int i = blockIdx.x * 256 + threadIdx.x;
  if (i < 9 * 128 * 128) {
    int c = i & 127;
    int o = (i >> 7) & 127;
    int tap = i >> 14;
    WT[i] = f2bf(wo[((o * 128 + c) * 3 + tap / 3) * 3 + tap % 3]);
  } else {
    int j = i - 9 * 128 * 128;
    if (j < 3 * 16384) {
      int sel = j >> 14, rest = j & 16383;
      const float* w = sel == 0 ? wq : (sel == 1 ? wk : wv);
      WQKV[j] = f2bf(w[rest]);
    }
  }
}

// ---------------- K1: QKV 1x1 conv + window scatter ----------------
// grid (1024, 3): x = 128-pixel block, y = sel(q/k/v). block 256.
__global__ __launch_bounds__(256) void k_qkv(
    const float* __restrict__ x, const u16* __restrict__ WQKV,
    const float* __restrict__ bq, const float* __restrict__ bk,
    const float* __restrict__ bv,
    u16* __restrict__ Q, u16* __restrict__ K, u16* __restrict__ V) {
  const int sel = blockIdx.y;
  const u16* w = WQKV + sel * 16384;
  const float* bias = sel == 0 ? bq : (sel == 1 ? bk : bv);
  const int p0g = blockIdx.x * 128;
  const int b = p0g >> 16;
  const int pix0 = p0g & 65535;
  const int tid = threadIdx.x, lane = tid & 63, wid = tid >> 6;
  const int wr = wid >> 1, wc = wid & 1;

  __shared__ u16 Xt[128 * 36];   // [p][c(32) pad to 36]
  f32x4 acc[4][4] = {};
  const float* xb = x + (size_t)b * 128 * 65536 + pix0;

  for (int k0 = 0; k0 < 128; k0 += 32) {
    __syncthreads();
    #pragma unroll
    for (int j = 0; j < 2; ++j) {
      int lin = j * 256 + tid;          // 0..511
      int c = lin >> 4;                 // 0..31
      int ch = lin & 15;                // 8-pixel chunk
      const float* src = xb + (size_t)(k0 + c) * 65536 + ch * 8;
      float4 v0 = *(const float4*)src;
      float4 v1 = *(const float4*)(src + 4);
      u16* dst = &Xt[(ch * 8) * 36 + c];
      dst[0 * 36] = f2bf(v0.x); dst[1 * 36] = f2bf(v0.y);
      dst[2 * 36] = f2bf(v0.z); dst[3 * 36] = f2bf(v0.w);
      dst[4 * 36] = f2bf(v1.x); dst[5 * 36] = f2bf(v1.y);
      dst[6 * 36] = f2bf(v1.z); dst[7 * 36] = f2bf(v1.w);
    }
    __syncthreads();
    bf16x8 a[4], bb[4];
    #pragma unroll
    for (int m = 0; m < 4; ++m) {
      int o = wr * 64 + m * 16 + (lane & 15);
      a[m] = *(const bf16x8*)(w + o * 128 + k0 + (lane >> 4) * 8);
    }
    #pragma unroll
    for (int n = 0; n < 4; ++n) {
      int p = wc * 64 + n * 16 + (lane & 15);
      const u16* base = &Xt[p * 36 + (lane >> 4) * 8];
      bf16x4 lo = *(const bf16x4*)base;
      bf16x4 hi = *(const bf16x4*)(base + 4);
      bb[n] = __builtin_shufflevector(lo, hi, 0, 1, 2, 3, 4, 5, 6, 7);
    }
    #pragma unroll
    for (int m = 0; m < 4; ++m)
      #pragma unroll
      for (int n = 0; n < 4; ++n)
        acc[m][n] = __builtin_amdgcn_mfma_f32_16x16x32_bf16(a[m], bb[n], acc[m][n], 0, 0, 0);
  }
  // epilogue: bias + window scatter
  #pragma unroll
  for (int m = 0; m < 4; ++m) {
    int o0 = wr * 64 + m * 16 + ((lane >> 4) << 2);
    #pragma unroll
    for (int n = 0; n < 4; ++n) {
      int p = wc * 64 + n * 16 + (lane & 15);
      int pix = pix0 + p;
      int h = pix >> 8, wpx = pix & 255;
      int oh = h >> 3, ph = h & 7, ow = wpx >> 3, pw = wpx & 7;
      int s = oh * 32 + ow;
      #pragma unroll
      for (int j = 0; j < 4; ++j) {
        int o = o0 + j;
        int head = o >> 5, dph = o & 31;
        float v = acc[m][n][j] + bias[o];
        int d = dph * 64 + ph * 8 + pw;
        size_t idx = ((size_t)(b * 4 + head) * 1024 + s) * 2048 + d;
        u16 val = f2bf(v);
        if (sel == 0) Q[idx] = val;
        else if (sel == 1) K[idx] = val;
        else V[idx] = val;
      }
    }
  }
}

// ---------------- K2: ATT = Q K^T * scale ----------------
// grid (64, 8): x = 8x8 tiles of 128x128, y = bh. block 256.
__global__ __launch_bounds__(256) void k_qk(const u16* __restrict__ Q,
                                            const u16* __restrict__ K,
                                            float* __restrict__ ATT) {
  const int bh = blockIdx.y;
  const int tm = blockIdx.x & 7, tn = blockIdx.x >> 3;
  const int row0 = tm * 128, col0 = tn * 128;
  const int tid = threadIdx.x, lane = tid & 63, wid = tid >> 6;
  const int wr = wid >> 1, wc = wid & 1;
  __shared__ u16 As[128 * 32];
  __shared__ u16 Bs[128 * 32];
  const u16* Ab = Q + (size_t)bh * 1024 * 2048 + (size_t)row0 * 2048;
  const u16* Bb = K + (size_t)bh * 1024 * 2048 + (size_t)col0 * 2048;
  f32x4 acc[4][4] = {};
  const int lr = lane >> 2, lc = lane & 3;

  for (int k0 = 0; k0 < 2048; k0 += 32) {
    __syncthreads();
    const u16* s0 = Ab + (size_t)(wid * 16 + lr) * 2048 + k0 + lc * 8;
    gl2lds16(s0, &As[wid * 512]);
    gl2lds16(s0 + (size_t)64 * 2048, &As[2048 + wid * 512]);
    const u16* s1 = Bb + (size_t)(wid * 16 + lr) * 2048 + k0 + lc * 8;
    gl2lds16(s1, &Bs[wid * 512]);
    gl2lds16(s1 + (size_t)64 * 2048, &Bs[2048 + wid * 512]);
    asm volatile("s_waitcnt vmcnt(0)" ::: "memory");
    __syncthreads();
    bf16x8 a[4], bb[4];
    #pragma unroll
    for (int m = 0; m < 4; ++m)
      a[m] = *(const bf16x8*)&As[(wr * 64 + m * 16 + (lane & 15)) * 32 + (lane >> 4) * 8];
    #pragma unroll
    for (int n = 0; n < 4; ++n)
      bb[n] = *(const bf16x8*)&Bs[(wc * 64 + n * 16 + (lane & 15)) * 32 + (lane >> 4) * 8];
    #pragma unroll
    for (int m = 0; m < 4; ++m)
      #pragma unroll
      for (int n = 0; n < 4; ++n)
        acc[m][n] = __builtin_amdgcn_mfma_f32_16x16x32_bf16(a[m], bb[n], acc[m][n], 0, 0, 0);
  }
  const float scale = 0.02209708691207961f;  // 1/sqrt(2048)
  float* out = ATT + (size_t)bh * 1024 * 1024;
  #pragma unroll
  for (int m = 0; m < 4; ++m) {
    int r = row0 + wr * 64 + m * 16 + ((lane >> 4) << 2);
    #pragma unroll
    for (int n = 0; n < 4; ++n) {
      int cc = col0 + wc * 64 + n * 16 + (lane & 15);
      #pragma unroll
      for (int j = 0; j < 4; ++j)
        out[(size_t)(r + j) * 1024 + cc] = acc[m][n][j] * scale;
    }
  }
}

// ---------------- K3: row softmax (1024 fp32 -> 1024 bf16) ----------------
__global__ __launch_bounds__(256) void k_softmax(const float* __restrict__ ATT,
                                                 u16* __restrict__ P) {
  const int row = blockIdx.x;
  const float* a = ATT + (size_t)row * 1024;
  const int tid = threadIdx.x;
  float4 v = *(const float4*)(a + tid * 4);
  float mx = fmaxf(fmaxf(v.x, v.y), fmaxf(v.z, v.w));
  #pragma unroll
  for (int off = 32; off; off >>= 1) mx = fmaxf(mx, __shfl_xor(mx, off, 64));
  __shared__ float red[8];
  if ((tid & 63) == 0) red[tid >> 6] = mx;
  __syncthreads();
  mx = fmaxf(fmaxf(red[0], red[1]), fmaxf(red[2], red[3]));
  float e0 = __expf(v.x - mx), e1 = __expf(v.y - mx);
  float e2 = __expf(v.z - mx), e3 = __expf(v.w - mx);
  float s = e0 + e1 + e2 + e3;
  #pragma unroll
  for (int off = 32; off; off >>= 1) s += __shfl_xor(s, off, 64);
  if ((tid & 63) == 0) red[4 + (tid >> 6)] = s;
  __syncthreads();
  s = red[4] + red[5] + red[6] + red[7];
  float inv = 1.0f / s;
  u16x4 o = { f2bf(e0 * inv), f2bf(e1 * inv), f2bf(e2 * inv), f2bf(e3 * inv) };
  *(u16x4*)(P + (size_t)row * 1024 + tid * 4) = o;
}

// ---------------- K4: Y = P V (un-window to bchw, bf16) ----------------
// grid (128, 8): x = (tm 0..7, tn 0..15), y = bh. block 256.
__global__ __launch_bounds__(256) void k_pv(const u16* __restrict__ P,
                                            const u16* __restrict__ V,
                                            u16* __restrict__ Y) {
  const int bh = blockIdx.y;
  const int tm = blockIdx.x & 7, tn = blockIdx.x >> 3;
  const int row0 = tm * 128, col0 = tn * 128;   // rows s, cols dv
  const int tid = threadIdx.x, lane = tid & 63, wid = tid >> 6;
  const int wr = wid >> 1, wc = wid & 1;
  __shared__ u16 As[128 * 32];
  __shared__ u16 Bt[128 * 36];                  // [dv_local][s(32) pad 36]
  const u16* Pb = P + (size_t)bh * 1024 * 1024 + (size_t)row0 * 1024;
  const u16* Vb = V + (size_t)bh * 1024 * 2048 + col0;
  f32x4 acc[4][4] = {};
  const int lr = lane >> 2, lc = lane & 3;

  for (int k0 = 0; k0 < 1024; k0 += 32) {
    __syncthreads();
    const u16* s0 = Pb + (size_t)(wid * 16 + lr) * 1024 + k0 + lc * 8;
    gl2lds16(s0, &As[wid * 512]);
    gl2lds16(s0 + (size_t)64 * 1024, &As[2048 + wid * 512]);
    #pragma unroll
    for (int j = 0; j < 2; ++j) {
      int lin = j * 256 + tid;          // 0..511
      int sl = lin >> 4;                // 0..31
      int ch = lin & 15;                // dv chunk
      union { uint4 u; u16 e[8]; } d;
      d.u = *(const uint4*)(Vb + (size_t)(k0 + sl) * 2048 + ch * 8);
      #pragma unroll
      for (int e2 = 0; e2 < 8; ++e2) Bt[(ch * 8 + e2) * 36 + sl] = d.e[e2];
    }
    asm volatile("s_waitcnt vmcnt(0)" ::: "memory");
    __syncthreads();
    bf16x8 a[4], bb[4];
    #pragma unroll
    for (int m = 0; m < 4; ++m)
      a[m] = *(const bf16x8*)&As[(wr * 64 + m * 16 + (lane & 15)) * 32 + (lane >> 4) * 8];
    #pragma unroll
    for (int n = 0; n < 4; ++n) {
      const u16* base = &Bt[(wc * 64 + n * 16 + (lane & 15)) * 36 + (lane >> 4) * 8];
      bf16x4 lo = *(const bf16x4*)base;
      bf16x4 hi = *(const bf16x4*)(base + 4);
      bb[n] = __builtin_shufflevector(lo, hi, 0, 1, 2, 3, 4, 5, 6, 7);
    }
    #pragma unroll
    for (int m = 0; m < 4; ++m)
      #pragma unroll
      for (int n = 0; n < 4; ++n)
        acc[m][n] = __builtin_amdgcn_mfma_f32_16x16x32_bf16(a[m], bb[n], acc[m][n], 0, 0, 0);
  }
  const int b = bh >> 2, head = bh & 3;
  #pragma unroll
  for (int m = 0; m < 4; ++m) {
    int s0r = row0 + wr * 64 + m * 16 + ((lane >> 4) << 2);
    #pragma unroll
    for (int n = 0; n < 4; ++n) {
      int dv = col0 + wc * 64 + n * 16 + (lane & 15);
      int dph = dv >> 6, ph = (dv >> 3) & 7, pw = dv & 7;
      int c = head * 32 + dph;
      #pragma unroll
      for (int j = 0; j < 4; ++j) {
        int ss = s0r + j;
        int oh = ss >> 5, ow = ss & 31;
        int h = oh * 8 + ph, w2 = ow * 8 + pw;
        Y[(((size_t)b * 128 + c) << 16) + (h << 8) + w2] = f2bf(acc[m][n][j]);
      }
    }
  }
}

// ---------------- K5: 3x3 reflect conv + bias + LeakyReLU (fp32 out) ----------------
// grid (512, 2): x = h*2 + wchunk, y = b. block 256.
__global__ __launch_bounds__(256) void k_conv(const u16* __restrict__ Y,
                                              const u16* __restrict__ WT,
                                              const float* __restrict__ bo,
                                              float* __restrict__ out) {
  const int b = blockIdx.y;
  const int h = blockIdx.x >> 1;
  const int w0 = (blockIdx.x & 1) * 128;
  const int tid = threadIdx.x, lane = tid & 63, wid = tid >> 6;
  const int wr = wid >> 1, wc = wid & 1;
  __shared__ u16 Yt[130 * 132];                // [p 0..129][c pad 132]
  f32x4 acc[4][4] = {};
  const u16* Yb = Y + (size_t)b * 128 * 65536;

  for (int ky = 0; ky < 3; ++ky) {
    int row = h + ky - 1;
    row = row < 0 ? 1 : (row > 255 ? 254 : row);
    __syncthreads();
    #pragma unroll
    for (int j = 0; j < 8; ++j) {
      int lin = j * 256 + tid;          // 0..2047
      int c = lin >> 4;                 // 0..127
      int ch = lin & 15;
      union { uint4 u; u16 e[8]; } d;
      d.u = *(const uint4*)(Yb + ((size_t)c << 16) + (row << 8) + w0 + ch * 8);
      #pragma unroll
      for (int e2 = 0; e2 < 8; ++e2) Yt[(1 + ch * 8 + e2) * 132 + c] = d.e[e2];
    }
    {
      int c = tid & 127;
      int side = tid >> 7;
      int wg = side == 0 ? (w0 == 0 ? 1 : w0 - 1) : (w0 + 128 > 255 ? 254 : w0 + 128);
      int p = side == 0 ? 0 : 129;
      Yt[p * 132 + c] = Yb[((size_t)c << 16) + (row << 8) + wg];
    }
    __syncthreads();
    #pragma unroll
    for (int kx = 0; kx < 3; ++kx) {
      int tap = ky * 3 + kx;
      #pragma unroll
      for (int ck = 0; ck < 4; ++ck) {
        int c0 = ck * 32;
        bf16x8 a[4], bb[4];
        #pragma unroll
        for (int m = 0; m < 4; ++m) {
          int o = wr * 64 + m * 16 + (lane & 15);
          a[m] = *(const bf16x8*)(WT + ((size_t)tap * 128 + o) * 128 + c0 + (lane >> 4) * 8);
        }
        #pragma unroll
        for (int n = 0; n < 4; ++n) {
          int p = wc * 64 + n * 16 + (lane & 15) + kx;   // 0..129
          const u16* base = &Yt[p * 132 + c0 + (lane >> 4) * 8];
          bf16x4 lo = *(const bf16x4*)base;
          bf16x4 hi = *(const bf16x4*)(base + 4);
          bb[n] = __builtin_shufflevector(lo, hi, 0, 1, 2, 3, 4, 5, 6, 7);
        }
        #pragma unroll
        for (int m = 0; m < 4; ++m)
          #pragma unroll
          for (int n = 0; n < 4; ++n)
            acc[m][n] = __builtin_amdgcn_mfma_f32_16x16x32_bf16(a[m], bb[n], acc[m][n], 0, 0, 0);
      }
    }
  }
  #pragma unroll
  for (int m = 0; m < 4; ++m) {
    int o0 = wr * 64 + m * 16 + ((lane >> 4) << 2);
    #pragma unroll
    for (int n = 0; n < 4; ++n) {
      int p = wc * 64 + n * 16 + (lane & 15);
      #pragma unroll
      for (int j = 0; j < 4; ++j) {
        int o = o0 + j;
        float v = acc[m][n][j] + bo[o];
        v = v > 0.f ? v : 0.2f * v;
        out[(((size_t)b * 128 + o) << 16) + (h << 8) + w0 + p] = v;
      }
    }
  }
}

extern "C" void kernel_launch(void* const* d_in, const int* in_sizes, int n_in,
                              void* d_out, int out_size, void* d_ws, size_t ws_size,
                              hipStream_t stream) {
  const float* x  = (const float*)d_in[0];
  // d_in[1] = mask: dead code in reference (masked_fill result not assigned)
  const float* wq = (const float*)d_in[2];
  const float* bq = (const float*)d_in[3];
  const float* wk = (const float*)d_in[4];
  const float* bk = (const float*)d_in[5];
  const float* wv = (const float*)d_in[6];
  const float* bv = (const float*)d_in[7];
  const float* wo = (const float*)d_in[8];
  const float* bo = (const float*)d_in[9];

  char* ws = (char*)d_ws;
  u16*   WT   = (u16*)(ws);                                 // 288 KiB
  u16*   WQKV = (u16*)(ws + (size_t)(512 << 10));           // 96 KiB
  u16*   Q   = (u16*)(ws + (size_t)(1  << 20));             // 32 MiB
  u16*   K   = (u16*)(ws + (size_t)(33 << 20));             // 32 MiB
  u16*   V   = (u16*)(ws + (size_t)(65 << 20));             // 32 MiB
  float* ATT = (float*)(ws + (size_t)(97 << 20));           // 32 MiB
  u16*   P   = (u16*)(ws + (size_t)(129 << 20));            // 16 MiB
  u16*   Yb  = (u16*)(ws + (size_t)(145 << 20));            // 32 MiB
  float* outp = (float*)d_out;

  k_prep<<<768, 256, 0, stream>>>(wo, wq, wk, wv, WT, WQKV);
  k_qkv<<<dim3(1024, 3), 256, 0, stream>>>(x, WQKV, bq, bk, bv, Q, K, V);
  k_qk<<<dim3(64, 8), 256, 0, stream>>>(Q, K, ATT);
  k_softmax<<<8192, 256, 0, stream>>>(ATT, P);
  k_pv<<<dim3(128, 8), 256, 0, stream>>>(P, V, Yb);
  k_conv<<<dim3(512, 2), 256, 0, stream>>>(Yb, WT, bo, outp);
}

// Round 3
// 333.877 us; speedup vs baseline: 1.1308x; 1.1308x over previous
//
#include <hip/hip_runtime.h>
#include <hip/hip_bf16.h>
#include <stdint.h>

typedef unsigned short u16;
typedef __attribute__((ext_vector_type(8))) short bf16x8;
typedef __attribute__((ext_vector_type(4))) short bf16x4;
typedef __attribute__((ext_vector_type(4))) float f32x4;
typedef __attribute__((ext_vector_type(4))) unsigned short u16x4;

__device__ __forceinline__ float bf2f(u16 u) {
  union { unsigned i; float f; } c; c.i = ((unsigned)u) << 16; return c.f;
}
__device__ __forceinline__ u16 f2bf(float f) {
  union { float f; unsigned i; } c; c.f = f;
  unsigned r = c.i + 0x7FFFu + ((c.i >> 16) & 1u);
  return (u16)(r >> 16);
}
__device__ __forceinline__ void gl2lds16(const u16* g, u16* l) {
  __builtin_amdgcn_global_load_lds(
      (const __attribute__((address_space(1))) unsigned int*)(uintptr_t)g,
      (__attribute__((address_space(3))) unsigned int*)(uintptr_t)l,
      16, 0, 0);
}

// ---------------- K0: convert weights to bf16 ----------------
__global__ void k_prep(const float* __restrict__ wo, const float* __restrict__ wq,
                       const float* __restrict__ wk, const float* __restrict__ wv,
                       u16* __restrict__ WT, u16* __restrict__ WQKV) {
  int i = blockIdx.x * 256 + threadIdx.x;
  if (i < 9 * 128 * 128) {
    int c = i & 127;
    int o = (i >> 7) & 127;
    int tap = i >> 14;
    WT[i] = f2bf(wo[((o * 128 + c) * 3 + tap / 3) * 3 + tap % 3]);
  } else {
    int j = i - 9 * 128 * 128;
    if (j < 3 * 16384) {
      int sel = j >> 14, rest = j & 16383;
      const float* w = sel == 0 ? wq : (sel == 1 ? wk : wv);
      WQKV[j] = f2bf(w[rest]);
    }
  }
}

// ---------------- K1: fused QKV 1x1 conv + window scatter ----------------
// grid 1024: block covers 8h x 16w pixel tile (2 full windows). block 256.
// Q/K/V layout: [bh][s][d] with d = pixw*32 + dph  (pixw = ph*8+pw, dph = o&31)
__global__ __launch_bounds__(256) void k_qkv(
    const float* __restrict__ x, const u16* __restrict__ WQKV,
    const float* __restrict__ bq, const float* __restrict__ bk,
    const float* __restrict__ bv,
    u16* __restrict__ Q, u16* __restrict__ K, u16* __restrict__ V) {
  const int blk = blockIdx.x;
  const int b = blk >> 9;
  const int t = blk & 511;
  const int th = t >> 4, tw = t & 15;
  const int h0 = th * 8, w0 = tw * 16;
  const int s0 = th * 32 + tw * 2;
  const int tid = threadIdx.x, lane = tid & 63, wid = tid >> 6;
  const int wr = wid >> 1, wc = wid & 1;
  const int g = lane >> 4, l15 = lane & 15;

  __shared__ u16 Xt[128 * 136];   // [p][c] pitch 136 (272B, 16B-mult, 2-way banks)
  __shared__ u16 Ot[64 * 136];    // transpose-out half-tile

  // stage x (fp32 -> bf16), all 128 channels for the 128-pixel tile
  #pragma unroll
  for (int j = 0; j < 8; ++j) {
    int lin = j * 256 + tid;            // 0..2047
    int c = lin >> 4;
    int ci = lin & 15;
    int lh = ci >> 1, lw8 = (ci & 1) * 8;
    const float* src = x + (size_t)b * 8388608 + (size_t)c * 65536 + (h0 + lh) * 256 + w0 + lw8;
    float4 v0 = *(const float4*)src;
    float4 v1 = *(const float4*)(src + 4);
    u16* dst = &Xt[(size_t)(lh * 16 + lw8) * 136 + c];
    dst[0 * 136] = f2bf(v0.x); dst[1 * 136] = f2bf(v0.y);
    dst[2 * 136] = f2bf(v0.z); dst[3 * 136] = f2bf(v0.w);
    dst[4 * 136] = f2bf(v1.x); dst[5 * 136] = f2bf(v1.y);
    dst[6 * 136] = f2bf(v1.z); dst[7 * 136] = f2bf(v1.w);
  }
  __syncthreads();

  for (int sel = 0; sel < 3; ++sel) {
    const u16* w = WQKV + sel * 16384;
    const float* bias = sel == 0 ? bq : (sel == 1 ? bk : bv);
    u16* qkv = sel == 0 ? Q : (sel == 1 ? K : V);

    f32x4 acc[4][4] = {};
    #pragma unroll
    for (int k0 = 0; k0 < 128; k0 += 32) {
      bf16x8 a[4], bb[4];
      #pragma unroll
      for (int m = 0; m < 4; ++m) {
        int o = wr * 64 + m * 16 + l15;
        a[m] = *(const bf16x8*)(w + o * 128 + k0 + g * 8);
      }
      #pragma unroll
      for (int n = 0; n < 4; ++n) {
        int p = wc * 64 + n * 16 + l15;
        bb[n] = *(const bf16x8*)&Xt[p * 136 + k0 + g * 8];
      }
      #pragma unroll
      for (int m = 0; m < 4; ++m)
        #pragma unroll
        for (int n = 0; n < 4; ++n)
          acc[m][n] = __builtin_amdgcn_mfma_f32_16x16x32_bf16(a[m], bb[n], acc[m][n], 0, 0, 0);
    }

    // bias vectors for this thread's 16 output channels
    float4 bias4[4];
    #pragma unroll
    for (int m = 0; m < 4; ++m)
      bias4[m] = *(const float4*)&bias[wr * 64 + m * 16 + g * 4];

    // epilogue in 2 halves (p 0..63, 64..127) through Ot
    #pragma unroll
    for (int h2 = 0; h2 < 2; ++h2) {
      __syncthreads();
      if (wc == h2) {
        #pragma unroll
        for (int m = 0; m < 4; ++m) {
          int o0 = wr * 64 + m * 16 + g * 4;
          #pragma unroll
          for (int n = 0; n < 4; ++n) {
            int p = n * 16 + l15;        // p within half
            u16x4 pk = { f2bf(acc[m][n][0] + bias4[m].x),
                         f2bf(acc[m][n][1] + bias4[m].y),
                         f2bf(acc[m][n][2] + bias4[m].z),
                         f2bf(acc[m][n][3] + bias4[m].w) };
            *(u16x4*)&Ot[p * 136 + o0] = pk;
          }
        }
      }
      __syncthreads();
      // write half: 1024 chunks of 16B, contiguous 2KB runs per (head,s2)
      #pragma unroll
      for (int it = 0; it < 4; ++it) {
        int ci = it * 256 + tid;          // 0..1023
        int hs = ci >> 7;                 // head*2+s2
        int rem = ci & 127;
        int head = hs >> 1, s2 = hs & 1;
        int pixw = h2 * 32 + (rem >> 2);
        int dphc = rem & 3;
        int pl = (pixw >> 3) * 16 + s2 * 8 + (pixw & 7) - h2 * 64;
        bf16x8 vv = *(const bf16x8*)&Ot[pl * 136 + head * 32 + dphc * 8];
        size_t gaddr = ((size_t)((b * 4 + head) * 1024 + s0 + s2)) * 2048 + pixw * 32 + dphc * 8;
        *(bf16x8*)(qkv + gaddr) = vv;
      }
    }
  }
}

// ---------------- K2: ATT = Q K^T * scale ----------------
__global__ __launch_bounds__(256) void k_qk(const u16* __restrict__ Q,
                                            const u16* __restrict__ K,
                                            float* __restrict__ ATT) {
  const int bh = blockIdx.y;
  const int tm = blockIdx.x & 7, tn = blockIdx.x >> 3;
  const int row0 = tm * 128, col0 = tn * 128;
  const int tid = threadIdx.x, lane = tid & 63, wid = tid >> 6;
  const int wr = wid >> 1, wc = wid & 1;
  __shared__ u16 As[128 * 32];
  __shared__ u16 Bs[128 * 32];
  const u16* Ab = Q + (size_t)bh * 1024 * 2048 + (size_t)row0 * 2048;
  const u16* Bb = K + (size_t)bh * 1024 * 2048 + (size_t)col0 * 2048;
  f32x4 acc[4][4] = {};
  const int lr = lane >> 2, lc = lane & 3;

  for (int k0 = 0; k0 < 2048; k0 += 32) {
    __syncthreads();
    const u16* s0 = Ab + (size_t)(wid * 16 + lr) * 2048 + k0 + lc * 8;
    gl2lds16(s0, &As[wid * 512]);
    gl2lds16(s0 + (size_t)64 * 2048, &As[2048 + wid * 512]);
    const u16* s1 = Bb + (size_t)(wid * 16 + lr) * 2048 + k0 + lc * 8;
    gl2lds16(s1, &Bs[wid * 512]);
    gl2lds16(s1 + (size_t)64 * 2048, &Bs[2048 + wid * 512]);
    asm volatile("s_waitcnt vmcnt(0)" ::: "memory");
    __syncthreads();
    bf16x8 a[4], bb[4];
    #pragma unroll
    for (int m = 0; m < 4; ++m)
      a[m] = *(const bf16x8*)&As[(wr * 64 + m * 16 + (lane & 15)) * 32 + (lane >> 4) * 8];
    #pragma unroll
    for (int n = 0; n < 4; ++n)
      bb[n] = *(const bf16x8*)&Bs[(wc * 64 + n * 16 + (lane & 15)) * 32 + (lane >> 4) * 8];
    #pragma unroll
    for (int m = 0; m < 4; ++m)
      #pragma unroll
      for (int n = 0; n < 4; ++n)
        acc[m][n] = __builtin_amdgcn_mfma_f32_16x16x32_bf16(a[m], bb[n], acc[m][n], 0, 0, 0);
  }
  const float scale = 0.02209708691207961f;  // 1/sqrt(2048)
  float* out = ATT + (size_t)bh * 1024 * 1024;
  #pragma unroll
  for (int m = 0; m < 4; ++m) {
    int r = row0 + wr * 64 + m * 16 + ((lane >> 4) << 2);
    #pragma unroll
    for (int n = 0; n < 4; ++n) {
      int cc = col0 + wc * 64 + n * 16 + (lane & 15);
      #pragma unroll
      for (int j = 0; j < 4; ++j)
        out[(size_t)(r + j) * 1024 + cc] = acc[m][n][j] * scale;
    }
  }
}

// ---------------- K3: row softmax ----------------
__global__ __launch_bounds__(256) void k_softmax(const float* __restrict__ ATT,
                                                 u16* __restrict__ P) {
  const int row = blockIdx.x;
  const float* a = ATT + (size_t)row * 1024;
  const int tid = threadIdx.x;
  float4 v = *(const float4*)(a + tid * 4);
  float mx = fmaxf(fmaxf(v.x, v.y), fmaxf(v.z, v.w));
  #pragma unroll
  for (int off = 32; off; off >>= 1) mx = fmaxf(mx, __shfl_xor(mx, off, 64));
  __shared__ float red[8];
  if ((tid & 63) == 0) red[tid >> 6] = mx;
  __syncthreads();
  mx = fmaxf(fmaxf(red[0], red[1]), fmaxf(red[2], red[3]));
  float e0 = __expf(v.x - mx), e1 = __expf(v.y - mx);
  float e2 = __expf(v.z - mx), e3 = __expf(v.w - mx);
  float s = e0 + e1 + e2 + e3;
  #pragma unroll
  for (int off = 32; off; off >>= 1) s += __shfl_xor(s, off, 64);
  if ((tid & 63) == 0) red[4 + (tid >> 6)] = s;
  __syncthreads();
  s = red[4] + red[5] + red[6] + red[7];
  float inv = 1.0f / s;
  u16x4 o = { f2bf(e0 * inv), f2bf(e1 * inv), f2bf(e2 * inv), f2bf(e3 * inv) };
  *(u16x4*)(P + (size_t)row * 1024 + tid * 4) = o;
}

// ---------------- K4: Y = P V, write NHWC ----------------
// grid (128, 8): tm = blockIdx.x&7 (s tile), tn = >>3 (dv tile). block 256.
__global__ __launch_bounds__(256) void k_pv(const u16* __restrict__ P,
                                            const u16* __restrict__ V,
                                            u16* __restrict__ Yn) {
  const int bh = blockIdx.y;
  const int tm = blockIdx.x & 7, tn = blockIdx.x >> 3;
  const int row0 = tm * 128, col0 = tn * 128;
  const int tid = threadIdx.x, lane = tid & 63, wid = tid >> 6;
  const int wr = wid >> 1, wc = wid & 1;
  __shared__ __align__(16) u16 smem[17408];   // 34816 B
  u16* As = smem;            // 128*32
  u16* Bt = smem + 4096;     // 128*36
  u16* Ot = smem;            // 128*136 (epilogue reuse)
  const u16* Pb = P + (size_t)bh * 1024 * 1024 + (size_t)row0 * 1024;
  const u16* Vb = V + (size_t)bh * 1024 * 2048 + col0;
  f32x4 acc[4][4] = {};
  const int lr = lane >> 2, lc = lane & 3;

  for (int k0 = 0; k0 < 1024; k0 += 32) {
    __syncthreads();
    const u16* s0 = Pb + (size_t)(wid * 16 + lr) * 1024 + k0 + lc * 8;
    gl2lds16(s0, &As[wid * 512]);
    gl2lds16(s0 + (size_t)64 * 1024, &As[2048 + wid * 512]);
    #pragma unroll
    for (int j = 0; j < 2; ++j) {
      int lin = j * 256 + tid;
      int sl = lin >> 4;
      int ch = lin & 15;
      union { uint4 u; u16 e[8]; } d;
      d.u = *(const uint4*)(Vb + (size_t)(k0 + sl) * 2048 + ch * 8);
      #pragma unroll
      for (int e2 = 0; e2 < 8; ++e2) Bt[(ch * 8 + e2) * 36 + sl] = d.e[e2];
    }
    asm volatile("s_waitcnt vmcnt(0)" ::: "memory");
    __syncthreads();
    bf16x8 a[4], bb[4];
    #pragma unroll
    for (int m = 0; m < 4; ++m)
      a[m] = *(const bf16x8*)&As[(wr * 64 + m * 16 + (lane & 15)) * 32 + (lane >> 4) * 8];
    #pragma unroll
    for (int n = 0; n < 4; ++n) {
      const u16* base = &Bt[(wc * 64 + n * 16 + (lane & 15)) * 36 + (lane >> 4) * 8];
      bf16x4 lo = *(const bf16x4*)base;
      bf16x4 hi = *(const bf16x4*)(base + 4);
      bb[n] = __builtin_shufflevector(lo, hi, 0, 1, 2, 3, 4, 5, 6, 7);
    }
    #pragma unroll
    for (int m = 0; m < 4; ++m)
      #pragma unroll
      for (int n = 0; n < 4; ++n)
        acc[m][n] = __builtin_amdgcn_mfma_f32_16x16x32_bf16(a[m], bb[n], acc[m][n], 0, 0, 0);
  }

  // epilogue: acc -> Ot[s_local][dv_local] -> NHWC Y (64B runs)
  __syncthreads();
  #pragma unroll
  for (int m = 0; m < 4; ++m) {
    int r0 = wr * 64 + m * 16 + ((lane >> 4) << 2);
    #pragma unroll
    for (int n = 0; n < 4; ++n) {
      int dv = wc * 64 + n * 16 + (lane & 15);
      #pragma unroll
      for (int j = 0; j < 4; ++j)
        Ot[(r0 + j) * 136 + dv] = f2bf(acc[m][n][j]);
    }
  }
  __syncthreads();
  const int b = bh >> 2, head = bh & 3;
  const int pixw0 = tn * 4;
  #pragma unroll
  for (int it = 0; it < 8; ++it) {
    int ci = it * 256 + tid;            // 0..2047
    int sl = ci >> 4;
    int pxl = (ci >> 2) & 3;
    int dc = ci & 3;
    bf16x8 vv = *(const bf16x8*)&Ot[sl * 136 + pxl * 32 + dc * 8];
    int s = row0 + sl, oh = s >> 5, ow = s & 31;
    int pixw = pixw0 + pxl, ph = pixw >> 3, pw = pixw & 7;
    int h = oh * 8 + ph, w2 = ow * 8 + pw;
    size_t gaddr = (((size_t)(b * 256 + h) * 256) + w2) * 128 + head * 32 + dc * 8;
    *(bf16x8*)(Yn + gaddr) = vv;
  }
}

// ---------------- K5: 3x3 reflect conv + bias + LeakyReLU (NHWC in, NCHW fp32 out) ----------------
// grid (512, 2): x = h*2 + wchunk, y = b. block 256.
__global__ __launch_bounds__(256) void k_conv(const u16* __restrict__ Yn,
                                              const u16* __restrict__ WT,
                                              const float* __restrict__ bo,
                                              float* __restrict__ out) {
  const int b = blockIdx.y;
  const int h = blockIdx.x >> 1;
  const int w0 = (blockIdx.x & 1) * 128;
  const int tid = threadIdx.x, lane = tid & 63, wid = tid >> 6;
  const int wr = wid >> 1, wc = wid & 1;
  const int g = lane >> 4, l15 = lane & 15;
  __shared__ u16 Yt[132 * 128];          // [p 0..131][c 128], XOR-swizzled chunks
  f32x4 acc[4][4] = {};
  const int lr4 = lane >> 4;             // row-in-inst 0..3
  const int lc16 = lane & 15;            // chunk 0..15

  for (int ky = 0; ky < 3; ++ky) {
    int row = h + ky - 1;
    row = row < 0 ? 1 : (row > 255 ? 254 : row);
    __syncthreads();
    for (int j5 = wid; j5 < 33; j5 += 4) {
      int r0 = j5 * 4 + lr4;             // 0..131 LDS row
      int wsrc = w0 - 1 + r0;
      wsrc = wsrc < 0 ? 1 : (wsrc > 255 ? 254 : wsrc);
      const u16* src = Yn + (((size_t)(b * 256 + row) * 256) + wsrc) * 128 + (lc16 ^ (r0 & 7)) * 8;
      gl2lds16(src, &Yt[j5 * 512]);
    }
    asm volatile("s_waitcnt vmcnt(0)" ::: "memory");
    __syncthreads();
    #pragma unroll
    for (int kx = 0; kx < 3; ++kx) {
      int tap = ky * 3 + kx;
      #pragma unroll
      for (int ck = 0; ck < 4; ++ck) {
        bf16x8 a[4], bb[4];
        #pragma unroll
        for (int m = 0; m < 4; ++m) {
          int o = wr * 64 + m * 16 + l15;
          a[m] = *(const bf16x8*)(WT + ((size_t)tap * 128 + o) * 128 + ck * 32 + g * 8);
        }
        #pragma unroll
        for (int n = 0; n < 4; ++n) {
          int p = wc * 64 + n * 16 + l15 + kx;   // 0..129
          bb[n] = *(const bf16x8*)&Yt[p * 128 + ((((ck << 2) + g) ^ (p & 7)) << 3)];
        }
        #pragma unroll
        for (int m = 0; m < 4; ++m)
          #pragma unroll
          for (int n = 0; n < 4; ++n)
            acc[m][n] = __builtin_amdgcn_mfma_f32_16x16x32_bf16(a[m], bb[n], acc[m][n], 0, 0, 0);
      }
    }
  }
  #pragma unroll
  for (int m = 0; m < 4; ++m) {
    int o0 = wr * 64 + m * 16 + (g << 2);
    #pragma unroll
    for (int n = 0; n < 4; ++n) {
      int p = wc * 64 + n * 16 + l15;
      #pragma unroll
      for (int j = 0; j < 4; ++j) {
        int o = o0 + j;
        float v = acc[m][n][j] + bo[o];
        v = v > 0.f ? v : 0.2f * v;
        out[(((size_t)b * 128 + o) << 16) + (h << 8) + w0 + p] = v;
      }
    }
  }
}

extern "C" void kernel_launch(void* const* d_in, const int* in_sizes, int n_in,
                              void* d_out, int out_size, void* d_ws, size_t ws_size,
                              hipStream_t stream) {
  const float* x  = (const float*)d_in[0];
  // d_in[1] = mask: dead code in reference
  const float* wq = (const float*)d_in[2];
  const float* bq = (const float*)d_in[3];
  const float* wk = (const float*)d_in[4];
  const float* bk = (const float*)d_in[5];
  const float* wv = (const float*)d_in[6];
  const float* bv = (const float*)d_in[7];
  const float* wo = (const float*)d_in[8];
  const float* bo = (const float*)d_in[9];

  char* ws = (char*)d_ws;
  u16*   WT   = (u16*)(ws);                                 // 288 KiB
  u16*   WQKV = (u16*)(ws + (size_t)(512 << 10));           // 96 KiB
  u16*   Q   = (u16*)(ws + (size_t)(1  << 20));             // 32 MiB
  u16*   K   = (u16*)(ws + (size_t)(33 << 20));             // 32 MiB
  u16*   V   = (u16*)(ws + (size_t)(65 << 20));             // 32 MiB
  float* ATT = (float*)(ws + (size_t)(97 << 20));           // 32 MiB
  u16*   P   = (u16*)(ws + (size_t)(129 << 20));            // 16 MiB
  u16*   Yn  = (u16*)(ws + (size_t)(145 << 20));            // 32 MiB NHWC
  float* outp = (float*)d_out;

  k_prep<<<768, 256, 0, stream>>>(wo, wq, wk, wv, WT, WQKV);
  k_qkv<<<1024, 256, 0, stream>>>(x, WQKV, bq, bk, bv, Q, K, V);
  k_qk<<<dim3(64, 8), 256, 0, stream>>>(Q, K, ATT);
  k_softmax<<<8192, 256, 0, stream>>>(ATT, P);
  k_pv<<<dim3(128, 8), 256, 0, stream>>>(P, V, Yn);
  k_conv<<<dim3(512, 2), 256, 0, stream>>>(Yn, WT, bo, outp);
}

// Round 4
// 309.210 us; speedup vs baseline: 1.2210x; 1.0798x over previous
//
#include <hip/hip_runtime.h>
#include <hip/hip_bf16.h>
#include <stdint.h>

typedef unsigned short u16;
typedef __attribute__((ext_vector_type(8))) short bf16x8;
typedef __attribute__((ext_vector_type(4))) short bf16x4;
typedef __attribute__((ext_vector_type(4))) float f32x4;
typedef __attribute__((ext_vector_type(4))) unsigned short u16x4;

__device__ __forceinline__ float bf2f(u16 u) {
  union { unsigned i; float f; } c; c.i = ((unsigned)u) << 16; return c.f;
}
__device__ __forceinline__ u16 f2bf(float f) {
  union { float f; unsigned i; } c; c.f = f;
  unsigned r = c.i + 0x7FFFu + ((c.i >> 16) & 1u);
  return (u16)(r >> 16);
}
__device__ __forceinline__ void gl2lds16(const u16* g, u16* l) {
  __builtin_amdgcn_global_load_lds(
      (const __attribute__((address_space(1))) unsigned int*)(uintptr_t)g,
      (__attribute__((address_space(3))) unsigned int*)(uintptr_t)l,
      16, 0, 0);
}

// ---------------- K0: convert weights to bf16 ----------------
__global__ void k_prep(const float* __restrict__ wo, const float* __restrict__ wq,
                       const float* __restrict__ wk, const float* __restrict__ wv,
                       u16* __restrict__ WT, u16* __restrict__ WQKV) {
  int i = blockIdx.x * 256 + threadIdx.x;
  if (i < 9 * 128 * 128) {
    int c = i & 127;
    int o = (i >> 7) & 127;
    int tap = i >> 14;
    WT[i] = f2bf(wo[((o * 128 + c) * 3 + tap / 3) * 3 + tap % 3]);
  } else {
    int j = i - 9 * 128 * 128;
    if (j < 3 * 16384) {
      int sel = j >> 14, rest = j & 16383;
      const float* w = sel == 0 ? wq : (sel == 1 ? wk : wv);
      WQKV[j] = f2bf(w[rest]);
    }
  }
}

// ---------------- K1: fused QKV 1x1 conv + window scatter ----------------
// grid 1024: block covers 8h x 16w pixel tile (2 full windows). block 256.
// Q/K/V layout: [bh][s][d] with d = pixw*32 + dph  (pixw = ph*8+pw, dph = o&31)
__global__ __launch_bounds__(256) void k_qkv(
    const float* __restrict__ x, const u16* __restrict__ WQKV,
    const float* __restrict__ bq, const float* __restrict__ bk,
    const float* __restrict__ bv,
    u16* __restrict__ Q, u16* __restrict__ K, u16* __restrict__ V) {
  const int blk = blockIdx.x;
  const int b = blk >> 9;
  const int t = blk & 511;
  const int th = t >> 4, tw = t & 15;
  const int h0 = th * 8, w0 = tw * 16;
  const int s0 = th * 32 + tw * 2;
  const int tid = threadIdx.x, lane = tid & 63, wid = tid >> 6;
  const int wr = wid >> 1, wc = wid & 1;
  const int g = lane >> 4, l15 = lane & 15;

  __shared__ u16 Xt[128 * 136];   // [p][c] pitch 136
  __shared__ u16 Ot[64 * 136];    // transpose-out half-tile

  #pragma unroll
  for (int j = 0; j < 8; ++j) {
    int lin = j * 256 + tid;            // 0..2047
    int c = lin >> 4;
    int ci = lin & 15;
    int lh = ci >> 1, lw8 = (ci & 1) * 8;
    const float* src = x + (size_t)b * 8388608 + (size_t)c * 65536 + (h0 + lh) * 256 + w0 + lw8;
    float4 v0 = *(const float4*)src;
    float4 v1 = *(const float4*)(src + 4);
    u16* dst = &Xt[(size_t)(lh * 16 + lw8) * 136 + c];
    dst[0 * 136] = f2bf(v0.x); dst[1 * 136] = f2bf(v0.y);
    dst[2 * 136] = f2bf(v0.z); dst[3 * 136] = f2bf(v0.w);
    dst[4 * 136] = f2bf(v1.x); dst[5 * 136] = f2bf(v1.y);
    dst[6 * 136] = f2bf(v1.z); dst[7 * 136] = f2bf(v1.w);
  }
  __syncthreads();

  for (int sel = 0; sel < 3; ++sel) {
    const u16* w = WQKV + sel * 16384;
    const float* bias = sel == 0 ? bq : (sel == 1 ? bk : bv);
    u16* qkv = sel == 0 ? Q : (sel == 1 ? K : V);

    f32x4 acc[4][4] = {};
    #pragma unroll
    for (int k0 = 0; k0 < 128; k0 += 32) {
      bf16x8 a[4], bb[4];
      #pragma unroll
      for (int m = 0; m < 4; ++m) {
        int o = wr * 64 + m * 16 + l15;
        a[m] = *(const bf16x8*)(w + o * 128 + k0 + g * 8);
      }
      #pragma unroll
      for (int n = 0; n < 4; ++n) {
        int p = wc * 64 + n * 16 + l15;
        bb[n] = *(const bf16x8*)&Xt[p * 136 + k0 + g * 8];
      }
      #pragma unroll
      for (int m = 0; m < 4; ++m)
        #pragma unroll
        for (int n = 0; n < 4; ++n)
          acc[m][n] = __builtin_amdgcn_mfma_f32_16x16x32_bf16(a[m], bb[n], acc[m][n], 0, 0, 0);
    }

    float4 bias4[4];
    #pragma unroll
    for (int m = 0; m < 4; ++m)
      bias4[m] = *(const float4*)&bias[wr * 64 + m * 16 + g * 4];

    #pragma unroll
    for (int h2 = 0; h2 < 2; ++h2) {
      __syncthreads();
      if (wc == h2) {
        #pragma unroll
        for (int m = 0; m < 4; ++m) {
          int o0 = wr * 64 + m * 16 + g * 4;
          #pragma unroll
          for (int n = 0; n < 4; ++n) {
            int p = n * 16 + l15;        // p within half
            u16x4 pk = { f2bf(acc[m][n][0] + bias4[m].x),
                         f2bf(acc[m][n][1] + bias4[m].y),
                         f2bf(acc[m][n][2] + bias4[m].z),
                         f2bf(acc[m][n][3] + bias4[m].w) };
            *(u16x4*)&Ot[p * 136 + o0] = pk;
          }
        }
      }
      __syncthreads();
      #pragma unroll
      for (int it = 0; it < 4; ++it) {
        int ci = it * 256 + tid;          // 0..1023
        int hs = ci >> 7;                 // head*2+s2
        int rem = ci & 127;
        int head = hs >> 1, s2 = hs & 1;
        int pixw = h2 * 32 + (rem >> 2);
        int dphc = rem & 3;
        int pl = (pixw >> 3) * 16 + s2 * 8 + (pixw & 7) - h2 * 64;
        bf16x8 vv = *(const bf16x8*)&Ot[pl * 136 + head * 32 + dphc * 8];
        size_t gaddr = ((size_t)((b * 4 + head) * 1024 + s0 + s2)) * 2048 + pixw * 32 + dphc * 8;
        *(bf16x8*)(qkv + gaddr) = vv;
      }
    }
  }
}

// ---------------- K2: ATT = Q K^T * scale ----------------
__global__ __launch_bounds__(256) void k_qk(const u16* __restrict__ Q,
                                            const u16* __restrict__ K,
                                            float* __restrict__ ATT) {
  const int bh = blockIdx.y;
  const int tm = blockIdx.x & 7, tn = blockIdx.x >> 3;
  const int row0 = tm * 128, col0 = tn * 128;
  const int tid = threadIdx.x, lane = tid & 63, wid = tid >> 6;
  const int wr = wid >> 1, wc = wid & 1;
  __shared__ u16 As[128 * 32];
  __shared__ u16 Bs[128 * 32];
  const u16* Ab = Q + (size_t)bh * 1024 * 2048 + (size_t)row0 * 2048;
  const u16* Bb = K + (size_t)bh * 1024 * 2048 + (size_t)col0 * 2048;
  f32x4 acc[4][4] = {};
  const int lr = lane >> 2, lc = lane & 3;

  for (int k0 = 0; k0 < 2048; k0 += 32) {
    __syncthreads();
    const u16* s0 = Ab + (size_t)(wid * 16 + lr) * 2048 + k0 + lc * 8;
    gl2lds16(s0, &As[wid * 512]);
    gl2lds16(s0 + (size_t)64 * 2048, &As[2048 + wid * 512]);
    const u16* s1 = Bb + (size_t)(wid * 16 + lr) * 2048 + k0 + lc * 8;
    gl2lds16(s1, &Bs[wid * 512]);
    gl2lds16(s1 + (size_t)64 * 2048, &Bs[2048 + wid * 512]);
    asm volatile("s_waitcnt vmcnt(0)" ::: "memory");
    __syncthreads();
    bf16x8 a[4], bb[4];
    #pragma unroll
    for (int m = 0; m < 4; ++m)
      a[m] = *(const bf16x8*)&As[(wr * 64 + m * 16 + (lane & 15)) * 32 + (lane >> 4) * 8];
    #pragma unroll
    for (int n = 0; n < 4; ++n)
      bb[n] = *(const bf16x8*)&Bs[(wc * 64 + n * 16 + (lane & 15)) * 32 + (lane >> 4) * 8];
    #pragma unroll
    for (int m = 0; m < 4; ++m)
      #pragma unroll
      for (int n = 0; n < 4; ++n)
        acc[m][n] = __builtin_amdgcn_mfma_f32_16x16x32_bf16(a[m], bb[n], acc[m][n], 0, 0, 0);
  }
  const float scale = 0.02209708691207961f;  // 1/sqrt(2048)
  float* out = ATT + (size_t)bh * 1024 * 1024;
  #pragma unroll
  for (int m = 0; m < 4; ++m) {
    int r = row0 + wr * 64 + m * 16 + ((lane >> 4) << 2);
    #pragma unroll
    for (int n = 0; n < 4; ++n) {
      int cc = col0 + wc * 64 + n * 16 + (lane & 15);
      #pragma unroll
      for (int j = 0; j < 4; ++j)
        out[(size_t)(r + j) * 1024 + cc] = acc[m][n][j] * scale;
    }
  }
}

// ---------------- K3: row softmax ----------------
__global__ __launch_bounds__(256) void k_softmax(const float* __restrict__ ATT,
                                                 u16* __restrict__ P) {
  const int row = blockIdx.x;
  const float* a = ATT + (size_t)row * 1024;
  const int tid = threadIdx.x;
  float4 v = *(const float4*)(a + tid * 4);
  float mx = fmaxf(fmaxf(v.x, v.y), fmaxf(v.z, v.w));
  #pragma unroll
  for (int off = 32; off; off >>= 1) mx = fmaxf(mx, __shfl_xor(mx, off, 64));
  __shared__ float red[8];
  if ((tid & 63) == 0) red[tid >> 6] = mx;
  __syncthreads();
  mx = fmaxf(fmaxf(red[0], red[1]), fmaxf(red[2], red[3]));
  float e0 = __expf(v.x - mx), e1 = __expf(v.y - mx);
  float e2 = __expf(v.z - mx), e3 = __expf(v.w - mx);
  float s = e0 + e1 + e2 + e3;
  #pragma unroll
  for (int off = 32; off; off >>= 1) s += __shfl_xor(s, off, 64);
  if ((tid & 63) == 0) red[4 + (tid >> 6)] = s;
  __syncthreads();
  s = red[4] + red[5] + red[6] + red[7];
  float inv = 1.0f / s;
  u16x4 o = { f2bf(e0 * inv), f2bf(e1 * inv), f2bf(e2 * inv), f2bf(e3 * inv) };
  *(u16x4*)(P + (size_t)row * 1024 + tid * 4) = o;
}

// ---------------- K4: Y = P V, write NHWC ----------------
__global__ __launch_bounds__(256) void k_pv(const u16* __restrict__ P,
                                            const u16* __restrict__ V,
                                            u16* __restrict__ Yn) {
  const int bh = blockIdx.y;
  const int tm = blockIdx.x & 7, tn = blockIdx.x >> 3;
  const int row0 = tm * 128, col0 = tn * 128;
  const int tid = threadIdx.x, lane = tid & 63, wid = tid >> 6;
  const int wr = wid >> 1, wc = wid & 1;
  __shared__ __align__(16) u16 smem[17408];
  u16* As = smem;            // 128*32
  u16* Bt = smem + 4096;     // 128*36
  u16* Ot = smem;            // 128*136 (epilogue reuse)
  const u16* Pb = P + (size_t)bh * 1024 * 1024 + (size_t)row0 * 1024;
  const u16* Vb = V + (size_t)bh * 1024 * 2048 + col0;
  f32x4 acc[4][4] = {};
  const int lr = lane >> 2, lc = lane & 3;

  for (int k0 = 0; k0 < 1024; k0 += 32) {
    __syncthreads();
    const u16* s0 = Pb + (size_t)(wid * 16 + lr) * 1024 + k0 + lc * 8;
    gl2lds16(s0, &As[wid * 512]);
    gl2lds16(s0 + (size_t)64 * 1024, &As[2048 + wid * 512]);
    #pragma unroll
    for (int j = 0; j < 2; ++j) {
      int lin = j * 256 + tid;
      int sl = lin >> 4;
      int ch = lin & 15;
      union { uint4 u; u16 e[8]; } d;
      d.u = *(const uint4*)(Vb + (size_t)(k0 + sl) * 2048 + ch * 8);
      #pragma unroll
      for (int e2 = 0; e2 < 8; ++e2) Bt[(ch * 8 + e2) * 36 + sl] = d.e[e2];
    }
    asm volatile("s_waitcnt vmcnt(0)" ::: "memory");
    __syncthreads();
    bf16x8 a[4], bb[4];
    #pragma unroll
    for (int m = 0; m < 4; ++m)
      a[m] = *(const bf16x8*)&As[(wr * 64 + m * 16 + (lane & 15)) * 32 + (lane >> 4) * 8];
    #pragma unroll
    for (int n = 0; n < 4; ++n) {
      const u16* base = &Bt[(wc * 64 + n * 16 + (lane & 15)) * 36 + (lane >> 4) * 8];
      bf16x4 lo = *(const bf16x4*)base;
      bf16x4 hi = *(const bf16x4*)(base + 4);
      bb[n] = __builtin_shufflevector(lo, hi, 0, 1, 2, 3, 4, 5, 6, 7);
    }
    #pragma unroll
    for (int m = 0; m < 4; ++m)
      #pragma unroll
      for (int n = 0; n < 4; ++n)
        acc[m][n] = __builtin_amdgcn_mfma_f32_16x16x32_bf16(a[m], bb[n], acc[m][n], 0, 0, 0);
  }

  __syncthreads();
  #pragma unroll
  for (int m = 0; m < 4; ++m) {
    int r0 = wr * 64 + m * 16 + ((lane >> 4) << 2);
    #pragma unroll
    for (int n = 0; n < 4; ++n) {
      int dv = wc * 64 + n * 16 + (lane & 15);
      #pragma unroll
      for (int j = 0; j < 4; ++j)
        Ot[(r0 + j) * 136 + dv] = f2bf(acc[m][n][j]);
    }
  }
  __syncthreads();
  const int b = bh >> 2, head = bh & 3;
  const int pixw0 = tn * 4;
  #pragma unroll
  for (int it = 0; it < 8; ++it) {
    int ci = it * 256 + tid;            // 0..2047
    int sl = ci >> 4;
    int pxl = (ci >> 2) & 3;
    int dc = ci & 3;
    bf16x8 vv = *(const bf16x8*)&Ot[sl * 136 + pxl * 32 + dc * 8];
    int s = row0 + sl, oh = s >> 5, ow = s & 31;
    int pixw = pixw0 + pxl, ph = pixw >> 3, pw = pixw & 7;
    int h = oh * 8 + ph, w2 = ow * 8 + pw;
    size_t gaddr = (((size_t)(b * 256 + h) * 256) + w2) * 128 + head * 32 + dc * 8;
    *(bf16x8*)(Yn + gaddr) = vv;
  }
}

// ---------------- K5: 3x3 reflect conv + bias + LeakyReLU (NHWC in, NCHW fp32 out) ----------------
// grid (512, 2): x = h*2 + wchunk, y = b. block 256.
// Double-buffered row staging + per-kx WT register preload.
__global__ __launch_bounds__(256, 2) void k_conv(const u16* __restrict__ Yn,
                                                 const u16* __restrict__ WT,
                                                 const float* __restrict__ bo,
                                                 float* __restrict__ out) {
  const int b = blockIdx.y;
  const int h = blockIdx.x >> 1;
  const int w0 = (blockIdx.x & 1) * 128;
  const int tid = threadIdx.x, lane = tid & 63, wid = tid >> 6;
  const int wr = wid >> 1, wc = wid & 1;
  const int g = lane >> 4, l15 = lane & 15;
  __shared__ u16 Yt[2][132 * 128];       // [p 0..131][c 128], XOR-swizzled chunks
  f32x4 acc[4][4] = {};

  // stage one padded row (132 x 128ch) into buf
  auto stage = [&](int ky, int buf) {
    int row = h + ky - 1;
    row = row < 0 ? 1 : (row > 255 ? 254 : row);
    for (int j5 = wid; j5 < 33; j5 += 4) {
      int r0 = j5 * 4 + (lane >> 4);
      int wsrc = w0 - 1 + r0;
      wsrc = wsrc < 0 ? 1 : (wsrc > 255 ? 254 : wsrc);
      const u16* src = Yn + (((size_t)(b * 256 + row) * 256) + wsrc) * 128 + ((l15 ^ (r0 & 7)) * 8);
      gl2lds16(src, &Yt[buf][j5 * 512]);
    }
  };

  stage(0, 0);
  for (int ky = 0; ky < 3; ++ky) {
    const int cur = ky & 1;
    asm volatile("s_waitcnt vmcnt(0)" ::: "memory");
    __syncthreads();
    #pragma unroll
    for (int kx = 0; kx < 3; ++kx) {
      int tap = ky * 3 + kx;
      // batch-preload all 16 A-fragments for this kx (pipelined L2 loads)
      bf16x8 areg[4][4];
      #pragma unroll
      for (int ck = 0; ck < 4; ++ck)
        #pragma unroll
        for (int m = 0; m < 4; ++m) {
          int o = wr * 64 + m * 16 + l15;
          areg[ck][m] = *(const bf16x8*)(WT + ((size_t)tap * 128 + o) * 128 + ck * 32 + g * 8);
        }
      // issue next row's staging AFTER this kx's A-loads so the compiler's
      // A-wait (vmcnt leaves stage outstanding) doesn't drain the stage;
      // the stage drains at the next ky's vmcnt(0).
      if (kx == 2 && ky < 2) stage(ky + 1, cur ^ 1);
      #pragma unroll
      for (int ck = 0; ck < 4; ++ck) {
        bf16x8 bb[4];
        #pragma unroll
        for (int n = 0; n < 4; ++n) {
          int p = wc * 64 + n * 16 + l15 + kx;   // 0..129
          bb[n] = *(const bf16x8*)&Yt[cur][p * 128 + ((((ck << 2) + g) ^ (p & 7)) << 3)];
        }
        #pragma unroll
        for (int m = 0; m < 4; ++m)
          #pragma unroll
          for (int n = 0; n < 4; ++n)
            acc[m][n] = __builtin_amdgcn_mfma_f32_16x16x32_bf16(areg[ck][m], bb[n], acc[m][n], 0, 0, 0);
      }
    }
  }
  #pragma unroll
  for (int m = 0; m < 4; ++m) {
    int o0 = wr * 64 + m * 16 + (g << 2);
    #pragma unroll
    for (int n = 0; n < 4; ++n) {
      int p = wc * 64 + n * 16 + l15;
      #pragma unroll
      for (int j = 0; j < 4; ++j) {
        int o = o0 + j;
        float v = acc[m][n][j] + bo[o];
        v = v > 0.f ? v : 0.2f * v;
        out[(((size_t)b * 128 + o) << 16) + (h << 8) + w0 + p] = v;
      }
    }
  }
}

extern "C" void kernel_launch(void* const* d_in, const int* in_sizes, int n_in,
                              void* d_out, int out_size, void* d_ws, size_t ws_size,
                              hipStream_t stream) {
  const float* x  = (const float*)d_in[0];
  // d_in[1] = mask: dead code in reference
  const float* wq = (const float*)d_in[2];
  const float* bq = (const float*)d_in[3];
  const float* wk = (const float*)d_in[4];
  const float* bk = (const float*)d_in[5];
  const float* wv = (const float*)d_in[6];
  const float* bv = (const float*)d_in[7];
  const float* wo = (const float*)d_in[8];
  const float* bo = (const float*)d_in[9];

  char* ws = (char*)d_ws;
  u16*   WT   = (u16*)(ws);                                 // 288 KiB
  u16*   WQKV = (u16*)(ws + (size_t)(512 << 10));           // 96 KiB
  u16*   Q   = (u16*)(ws + (size_t)(1  << 20));             // 32 MiB
  u16*   K   = (u16*)(ws + (size_t)(33 << 20));             // 32 MiB
  u16*   V   = (u16*)(ws + (size_t)(65 << 20));             // 32 MiB
  float* ATT = (float*)(ws + (size_t)(97 << 20));           // 32 MiB
  u16*   P   = (u16*)(ws + (size_t)(129 << 20));            // 16 MiB
  u16*   Yn  = (u16*)(ws + (size_t)(145 << 20));            // 32 MiB NHWC
  float* outp = (float*)d_out;

  k_prep<<<768, 256, 0, stream>>>(wo, wq, wk, wv, WT, WQKV);
  k_qkv<<<1024, 256, 0, stream>>>(x, WQKV, bq, bk, bv, Q, K, V);
  k_qk<<<dim3(64, 8), 256, 0, stream>>>(Q, K, ATT);
  k_softmax<<<8192, 256, 0, stream>>>(ATT, P);
  k_pv<<<dim3(128, 8), 256, 0, stream>>>(P, V, Yn);
  k_conv<<<dim3(512, 2), 256, 0, stream>>>(Yn, WT, bo, outp);
}

// Round 5
// 277.527 us; speedup vs baseline: 1.3604x; 1.1142x over previous
//
#include <hip/hip_runtime.h>
#include <hip/hip_bf16.h>
#include <stdint.h>

typedef unsigned short u16;
typedef __attribute__((ext_vector_type(8))) short bf16x8;
typedef __attribute__((ext_vector_type(4))) short bf16x4;
typedef __attribute__((ext_vector_type(4))) float f32x4;
typedef __attribute__((ext_vector_type(4))) unsigned short u16x4;

__device__ __forceinline__ float bf2f(u16 u) {
  union { unsigned i; float f; } c; c.i = ((unsigned)u) << 16; return c.f;
}
__device__ __forceinline__ u16 f2bf(float f) {
  union { float f; unsigned i; } c; c.f = f;
  unsigned r = c.i + 0x7FFFu + ((c.i >> 16) & 1u);
  return (u16)(r >> 16);
}
__device__ __forceinline__ void gl2lds16(const u16* g, u16* l) {
  __builtin_amdgcn_global_load_lds(
      (const __attribute__((address_space(1))) unsigned int*)(uintptr_t)g,
      (__attribute__((address_space(3))) unsigned int*)(uintptr_t)l,
      16, 0, 0);
}

// ---------------- K0: convert weights to bf16 ----------------
__global__ void k_prep(const float* __restrict__ wo, const float* __restrict__ wq,
                       const float* __restrict__ wk, const float* __restrict__ wv,
                       u16* __restrict__ WT, u16* __restrict__ WQKV) {
  int i = blockIdx.x * 256 + threadIdx.x;
  if (i < 9 * 128 * 128) {
    int c = i & 127;
    int o = (i >> 7) & 127;
    int tap = i >> 14;
    WT[i] = f2bf(wo[((o * 128 + c) * 3 + tap / 3) * 3 + tap % 3]);
  } else {
    int j = i - 9 * 128 * 128;
    if (j < 3 * 16384) {
      int sel = j >> 14, rest = j & 16383;
      const float* w = sel == 0 ? wq : (sel == 1 ? wk : wv);
      WQKV[j] = f2bf(w[rest]);
    }
  }
}

// ---------------- K1: fused QKV 1x1 conv + window scatter ----------------
// grid 1024: block covers 8h x 16w pixel tile (2 full windows). block 256.
// Q/K/V layout: [bh][s][d] with d = pixw*32 + dph  (pixw = ph*8+pw, dph = o&31)
__global__ __launch_bounds__(256) void k_qkv(
    const float* __restrict__ x, const u16* __restrict__ WQKV,
    const float* __restrict__ bq, const float* __restrict__ bk,
    const float* __restrict__ bv,
    u16* __restrict__ Q, u16* __restrict__ K, u16* __restrict__ V) {
  const int blk = blockIdx.x;
  const int b = blk >> 9;
  const int t = blk & 511;
  const int th = t >> 4, tw = t & 15;
  const int h0 = th * 8, w0 = tw * 16;
  const int s0 = th * 32 + tw * 2;
  const int tid = threadIdx.x, lane = tid & 63, wid = tid >> 6;
  const int wr = wid >> 1, wc = wid & 1;
  const int g = lane >> 4, l15 = lane & 15;

  __shared__ u16 Xt[128 * 136];   // [p][c] pitch 136
  __shared__ u16 Ot[64 * 136];    // transpose-out half-tile

  #pragma unroll
  for (int j = 0; j < 8; ++j) {
    int lin = j * 256 + tid;            // 0..2047
    int c = lin >> 4;
    int ci = lin & 15;
    int lh = ci >> 1, lw8 = (ci & 1) * 8;
    const float* src = x + (size_t)b * 8388608 + (size_t)c * 65536 + (h0 + lh) * 256 + w0 + lw8;
    float4 v0 = *(const float4*)src;
    float4 v1 = *(const float4*)(src + 4);
    u16* dst = &Xt[(size_t)(lh * 16 + lw8) * 136 + c];
    dst[0 * 136] = f2bf(v0.x); dst[1 * 136] = f2bf(v0.y);
    dst[2 * 136] = f2bf(v0.z); dst[3 * 136] = f2bf(v0.w);
    dst[4 * 136] = f2bf(v1.x); dst[5 * 136] = f2bf(v1.y);
    dst[6 * 136] = f2bf(v1.z); dst[7 * 136] = f2bf(v1.w);
  }
  __syncthreads();

  for (int sel = 0; sel < 3; ++sel) {
    const u16* w = WQKV + sel * 16384;
    const float* bias = sel == 0 ? bq : (sel == 1 ? bk : bv);
    u16* qkv = sel == 0 ? Q : (sel == 1 ? K : V);

    f32x4 acc[4][4] = {};
    #pragma unroll
    for (int k0 = 0; k0 < 128; k0 += 32) {
      bf16x8 a[4], bb[4];
      #pragma unroll
      for (int m = 0; m < 4; ++m) {
        int o = wr * 64 + m * 16 + l15;
        a[m] = *(const bf16x8*)(w + o * 128 + k0 + g * 8);
      }
      #pragma unroll
      for (int n = 0; n < 4; ++n) {
        int p = wc * 64 + n * 16 + l15;
        bb[n] = *(const bf16x8*)&Xt[p * 136 + k0 + g * 8];
      }
      #pragma unroll
      for (int m = 0; m < 4; ++m)
        #pragma unroll
        for (int n = 0; n < 4; ++n)
          acc[m][n] = __builtin_amdgcn_mfma_f32_16x16x32_bf16(a[m], bb[n], acc[m][n], 0, 0, 0);
    }

    float4 bias4[4];
    #pragma unroll
    for (int m = 0; m < 4; ++m)
      bias4[m] = *(const float4*)&bias[wr * 64 + m * 16 + g * 4];

    #pragma unroll
    for (int h2 = 0; h2 < 2; ++h2) {
      __syncthreads();
      if (wc == h2) {
        #pragma unroll
        for (int m = 0; m < 4; ++m) {
          int o0 = wr * 64 + m * 16 + g * 4;
          #pragma unroll
          for (int n = 0; n < 4; ++n) {
            int p = n * 16 + l15;        // p within half
            u16x4 pk = { f2bf(acc[m][n][0] + bias4[m].x),
                         f2bf(acc[m][n][1] + bias4[m].y),
                         f2bf(acc[m][n][2] + bias4[m].z),
                         f2bf(acc[m][n][3] + bias4[m].w) };
            *(u16x4*)&Ot[p * 136 + o0] = pk;
          }
        }
      }
      __syncthreads();
      #pragma unroll
      for (int it = 0; it < 4; ++it) {
        int ci = it * 256 + tid;          // 0..1023
        int hs = ci >> 7;                 // head*2+s2
        int rem = ci & 127;
        int head = hs >> 1, s2 = hs & 1;
        int pixw = h2 * 32 + (rem >> 2);
        int dphc = rem & 3;
        int pl = (pixw >> 3) * 16 + s2 * 8 + (pixw & 7) - h2 * 64;
        bf16x8 vv = *(const bf16x8*)&Ot[pl * 136 + head * 32 + dphc * 8];
        size_t gaddr = ((size_t)((b * 4 + head) * 1024 + s0 + s2)) * 2048 + pixw * 32 + dphc * 8;
        *(bf16x8*)(qkv + gaddr) = vv;
      }
    }
  }
}

// ---------------- K2: ATT = Q K^T * scale ----------------
__global__ __launch_bounds__(256) void k_qk(const u16* __restrict__ Q,
                                            const u16* __restrict__ K,
                                            float* __restrict__ ATT) {
  const int bh = blockIdx.y;
  const int tm = blockIdx.x & 7, tn = blockIdx.x >> 3;
  const int row0 = tm * 128, col0 = tn * 128;
  const int tid = threadIdx.x, lane = tid & 63, wid = tid >> 6;
  const int wr = wid >> 1, wc = wid & 1;
  __shared__ u16 As[128 * 32];
  __shared__ u16 Bs[128 * 32];
  const u16* Ab = Q + (size_t)bh * 1024 * 2048 + (size_t)row0 * 2048;
  const u16* Bb = K + (size_t)bh * 1024 * 2048 + (size_t)col0 * 2048;
  f32x4 acc[4][4] = {};
  const int lr = lane >> 2, lc = lane & 3;

  for (int k0 = 0; k0 < 2048; k0 += 32) {
    __syncthreads();
    const u16* s0 = Ab + (size_t)(wid * 16 + lr) * 2048 + k0 + lc * 8;
    gl2lds16(s0, &As[wid * 512]);
    gl2lds16(s0 + (size_t)64 * 2048, &As[2048 + wid * 512]);
    const u16* s1 = Bb + (size_t)(wid * 16 + lr) * 2048 + k0 + lc * 8;
    gl2lds16(s1, &Bs[wid * 512]);
    gl2lds16(s1 + (size_t)64 * 2048, &Bs[2048 + wid * 512]);
    asm volatile("s_waitcnt vmcnt(0)" ::: "memory");
    __syncthreads();
    bf16x8 a[4], bb[4];
    #pragma unroll
    for (int m = 0; m < 4; ++m)
      a[m] = *(const bf16x8*)&As[(wr * 64 + m * 16 + (lane & 15)) * 32 + (lane >> 4) * 8];
    #pragma unroll
    for (int n = 0; n < 4; ++n)
      bb[n] = *(const bf16x8*)&Bs[(wc * 64 + n * 16 + (lane & 15)) * 32 + (lane >> 4) * 8];
    #pragma unroll
    for (int m = 0; m < 4; ++m)
      #pragma unroll
      for (int n = 0; n < 4; ++n)
        acc[m][n] = __builtin_amdgcn_mfma_f32_16x16x32_bf16(a[m], bb[n], acc[m][n], 0, 0, 0);
  }
  const float scale = 0.02209708691207961f;  // 1/sqrt(2048)
  float* out = ATT + (size_t)bh * 1024 * 1024;
  #pragma unroll
  for (int m = 0; m < 4; ++m) {
    int r = row0 + wr * 64 + m * 16 + ((lane >> 4) << 2);
    #pragma unroll
    for (int n = 0; n < 4; ++n) {
      int cc = col0 + wc * 64 + n * 16 + (lane & 15);
      #pragma unroll
      for (int j = 0; j < 4; ++j)
        out[(size_t)(r + j) * 1024 + cc] = acc[m][n][j] * scale;
    }
  }
}

// ---------------- K2b: VT[bh][dv][s] = V[bh][s][dv] (tiled transpose) ----------------
// grid (128, 8): x = ts(0..7)*16? -> ts = x&7, td = x>>3. block 256. tile 128s x 128dv.
__global__ __launch_bounds__(256) void k_vt(const u16* __restrict__ V,
                                            u16* __restrict__ VT) {
  const int bh = blockIdx.y;
  const int ts = blockIdx.x & 7, td = blockIdx.x >> 3;
  const int s0 = ts * 128, d0 = td * 128;
  const int tid = threadIdx.x;
  __shared__ u16 T[128 * 128];   // [dv][s], s-chunk XOR-swizzled by (dv>>3)&15
  const u16* Vb = V + (size_t)bh * 1024 * 2048 + (size_t)s0 * 2048 + d0;

  #pragma unroll
  for (int pass = 0; pass < 8; ++pass) {
    int r = pass * 16 + (tid >> 4);      // s-local
    int c8 = (tid & 15) * 8;             // dv-local base
    union { uint4 u; u16 e[8]; } d;
    d.u = *(const uint4*)(Vb + (size_t)r * 2048 + c8);
    int chunk = (r >> 3) ^ ((c8 >> 3) & 15);
    u16* dst = &T[0];
    #pragma unroll
    for (int e = 0; e < 8; ++e)
      dst[(c8 + e) * 128 + chunk * 8 + (r & 7)] = d.e[e];
  }
  __syncthreads();
  u16* VTb = VT + (size_t)bh * 2048 * 1024 + (size_t)d0 * 1024 + s0;
  #pragma unroll
  for (int pass = 0; pass < 8; ++pass) {
    int rd = pass * 16 + (tid >> 4);     // dv-local
    int c8 = (tid & 15) * 8;             // s-local base
    int chunk = (c8 >> 3) ^ ((rd >> 3) & 15);
    bf16x8 v = *(const bf16x8*)&T[rd * 128 + chunk * 8];
    *(bf16x8*)(VTb + (size_t)rd * 1024 + c8) = v;
  }
}

// ---------------- K3: row softmax ----------------
__global__ __launch_bounds__(256) void k_softmax(const float* __restrict__ ATT,
                                                 u16* __restrict__ P) {
  const int row = blockIdx.x;
  const float* a = ATT + (size_t)row * 1024;
  const int tid = threadIdx.x;
  float4 v = *(const float4*)(a + tid * 4);
  float mx = fmaxf(fmaxf(v.x, v.y), fmaxf(v.z, v.w));
  #pragma unroll
  for (int off = 32; off; off >>= 1) mx = fmaxf(mx, __shfl_xor(mx, off, 64));
  __shared__ float red[8];
  if ((tid & 63) == 0) red[tid >> 6] = mx;
  __syncthreads();
  mx = fmaxf(fmaxf(red[0], red[1]), fmaxf(red[2], red[3]));
  float e0 = __expf(v.x - mx), e1 = __expf(v.y - mx);
  float e2 = __expf(v.z - mx), e3 = __expf(v.w - mx);
  float s = e0 + e1 + e2 + e3;
  #pragma unroll
  for (int off = 32; off; off >>= 1) s += __shfl_xor(s, off, 64);
  if ((tid & 63) == 0) red[4 + (tid >> 6)] = s;
  __syncthreads();
  s = red[4] + red[5] + red[6] + red[7];
  float inv = 1.0f / s;
  u16x4 o = { f2bf(e0 * inv), f2bf(e1 * inv), f2bf(e2 * inv), f2bf(e3 * inv) };
  *(u16x4*)(P + (size_t)row * 1024 + tid * 4) = o;
}

// ---------------- K4: Y = P V via VT, write NHWC ----------------
// grid (128, 8): tm = blockIdx.x&7 (s tile), tn = >>3 (dv tile). block 256.
__global__ __launch_bounds__(256) void k_pv(const u16* __restrict__ P,
                                            const u16* __restrict__ VT,
                                            u16* __restrict__ Yn) {
  const int bh = blockIdx.y;
  const int tm = blockIdx.x & 7, tn = blockIdx.x >> 3;
  const int row0 = tm * 128, col0 = tn * 128;
  const int tid = threadIdx.x, lane = tid & 63, wid = tid >> 6;
  const int wr = wid >> 1, wc = wid & 1;
  __shared__ __align__(16) u16 smem[17408];
  u16* As = smem;            // 128*32
  u16* Bs = smem + 4096;     // 128*32
  u16* Ot = smem;            // 128*136 (epilogue reuse)
  const u16* Pb = P + (size_t)bh * 1024 * 1024 + (size_t)row0 * 1024;
  const u16* VTb = VT + (size_t)bh * 2048 * 1024 + (size_t)col0 * 1024;
  f32x4 acc[4][4] = {};
  const int lr = lane >> 2, lc = lane & 3;

  for (int k0 = 0; k0 < 1024; k0 += 32) {
    __syncthreads();
    const u16* s0 = Pb + (size_t)(wid * 16 + lr) * 1024 + k0 + lc * 8;
    gl2lds16(s0, &As[wid * 512]);
    gl2lds16(s0 + (size_t)64 * 1024, &As[2048 + wid * 512]);
    const u16* s1 = VTb + (size_t)(wid * 16 + lr) * 1024 + k0 + lc * 8;
    gl2lds16(s1, &Bs[wid * 512]);
    gl2lds16(s1 + (size_t)64 * 1024, &Bs[2048 + wid * 512]);
    asm volatile("s_waitcnt vmcnt(0)" ::: "memory");
    __syncthreads();
    bf16x8 a[4], bb[4];
    #pragma unroll
    for (int m = 0; m < 4; ++m)
      a[m] = *(const bf16x8*)&As[(wr * 64 + m * 16 + (lane & 15)) * 32 + (lane >> 4) * 8];
    #pragma unroll
    for (int n = 0; n < 4; ++n)
      bb[n] = *(const bf16x8*)&Bs[(wc * 64 + n * 16 + (lane & 15)) * 32 + (lane >> 4) * 8];
    #pragma unroll
    for (int m = 0; m < 4; ++m)
      #pragma unroll
      for (int n = 0; n < 4; ++n)
        acc[m][n] = __builtin_amdgcn_mfma_f32_16x16x32_bf16(a[m], bb[n], acc[m][n], 0, 0, 0);
  }

  __syncthreads();
  #pragma unroll
  for (int m = 0; m < 4; ++m) {
    int r0 = wr * 64 + m * 16 + ((lane >> 4) << 2);
    #pragma unroll
    for (int n = 0; n < 4; ++n) {
      int dv = wc * 64 + n * 16 + (lane & 15);
      #pragma unroll
      for (int j = 0; j < 4; ++j)
        Ot[(r0 + j) * 136 + dv] = f2bf(acc[m][n][j]);
    }
  }
  __syncthreads();
  const int b = bh >> 2, head = bh & 3;
  const int pixw0 = tn * 4;
  #pragma unroll
  for (int it = 0; it < 8; ++it) {
    int ci = it * 256 + tid;            // 0..2047
    int sl = ci >> 4;
    int pxl = (ci >> 2) & 3;
    int dc = ci & 3;
    bf16x8 vv = *(const bf16x8*)&Ot[sl * 136 + pxl * 32 + dc * 8];
    int s = row0 + sl, oh = s >> 5, ow = s & 31;
    int pixw = pixw0 + pxl, ph = pixw >> 3, pw = pixw & 7;
    int h = oh * 8 + ph, w2 = ow * 8 + pw;
    size_t gaddr = (((size_t)(b * 256 + h) * 256) + w2) * 128 + head * 32 + dc * 8;
    *(bf16x8*)(Yn + gaddr) = vv;
  }
}

// ---------------- K5: 3x3 reflect conv + bias + LeakyReLU (NHWC in, NCHW fp32 out) ----------------
// grid (512, 2): x = h*2 + wchunk, y = b. block 256.
// Double-buffered row staging + per-kx WT register preload.
__global__ __launch_bounds__(256, 2) void k_conv(const u16* __restrict__ Yn,
                                                 const u16* __restrict__ WT,
                                                 const float* __restrict__ bo,
                                                 float* __restrict__ out) {
  const int b = blockIdx.y;
  const int h = blockIdx.x >> 1;
  const int w0 = (blockIdx.x & 1) * 128;
  const int tid = threadIdx.x, lane = tid & 63, wid = tid >> 6;
  const int wr = wid >> 1, wc = wid & 1;
  const int g = lane >> 4, l15 = lane & 15;
  __shared__ u16 Yt[2][132 * 128];       // [p 0..131][c 128], XOR-swizzled chunks
  f32x4 acc[4][4] = {};

  auto stage = [&](int ky, int buf) {
    int row = h + ky - 1;
    row = row < 0 ? 1 : (row > 255 ? 254 : row);
    for (int j5 = wid; j5 < 33; j5 += 4) {
      int r0 = j5 * 4 + (lane >> 4);
      int wsrc = w0 - 1 + r0;
      wsrc = wsrc < 0 ? 1 : (wsrc > 255 ? 254 : wsrc);
      const u16* src = Yn + (((size_t)(b * 256 + row) * 256) + wsrc) * 128 + ((l15 ^ (r0 & 7)) * 8);
      gl2lds16(src, &Yt[buf][j5 * 512]);
    }
  };

  stage(0, 0);
  for (int ky = 0; ky < 3; ++ky) {
    const int cur = ky & 1;
    asm volatile("s_waitcnt vmcnt(0)" ::: "memory");
    __syncthreads();
    #pragma unroll
    for (int kx = 0; kx < 3; ++kx) {
      int tap = ky * 3 + kx;
      bf16x8 areg[4][4];
      #pragma unroll
      for (int ck = 0; ck < 4; ++ck)
        #pragma unroll
        for (int m = 0; m < 4; ++m) {
          int o = wr * 64 + m * 16 + l15;
          areg[ck][m] = *(const bf16x8*)(WT + ((size_t)tap * 128 + o) * 128 + ck * 32 + g * 8);
        }
      if (kx == 2 && ky < 2) stage(ky + 1, cur ^ 1);
      #pragma unroll
      for (int ck = 0; ck < 4; ++ck) {
        bf16x8 bb[4];
        #pragma unroll
        for (int n = 0; n < 4; ++n) {
          int p = wc * 64 + n * 16 + l15 + kx;   // 0..129
          bb[n] = *(const bf16x8*)&Yt[cur][p * 128 + ((((ck << 2) + g) ^ (p & 7)) << 3)];
        }
        #pragma unroll
        for (int m = 0; m < 4; ++m)
          #pragma unroll
          for (int n = 0; n < 4; ++n)
            acc[m][n] = __builtin_amdgcn_mfma_f32_16x16x32_bf16(areg[ck][m], bb[n], acc[m][n], 0, 0, 0);
      }
    }
  }
  #pragma unroll
  for (int m = 0; m < 4; ++m) {
    int o0 = wr * 64 + m * 16 + (g << 2);
    #pragma unroll
    for (int n = 0; n < 4; ++n) {
      int p = wc * 64 + n * 16 + l15;
      #pragma unroll
      for (int j = 0; j < 4; ++j) {
        int o = o0 + j;
        float v = acc[m][n][j] + bo[o];
        v = v > 0.f ? v : 0.2f * v;
        out[(((size_t)b * 128 + o) << 16) + (h << 8) + w0 + p] = v;
      }
    }
  }
}

extern "C" void kernel_launch(void* const* d_in, const int* in_sizes, int n_in,
                              void* d_out, int out_size, void* d_ws, size_t ws_size,
                              hipStream_t stream) {
  const float* x  = (const float*)d_in[0];
  // d_in[1] = mask: dead code in reference
  const float* wq = (const float*)d_in[2];
  const float* bq = (const float*)d_in[3];
  const float* wk = (const float*)d_in[4];
  const float* bk = (const float*)d_in[5];
  const float* wv = (const float*)d_in[6];
  const float* bv = (const float*)d_in[7];
  const float* wo = (const float*)d_in[8];
  const float* bo = (const float*)d_in[9];

  char* ws = (char*)d_ws;
  u16*   WT   = (u16*)(ws);                                 // 288 KiB
  u16*   WQKV = (u16*)(ws + (size_t)(512 << 10));           // 96 KiB
  u16*   Q   = (u16*)(ws + (size_t)(1  << 20));             // 32 MiB (VT aliases after k_qk)
  u16*   K   = (u16*)(ws + (size_t)(33 << 20));             // 32 MiB
  u16*   V   = (u16*)(ws + (size_t)(65 << 20));             // 32 MiB
  float* ATT = (float*)(ws + (size_t)(97 << 20));           // 32 MiB
  u16*   P   = (u16*)(ws + (size_t)(129 << 20));            // 16 MiB
  u16*   Yn  = (u16*)(ws + (size_t)(145 << 20));            // 32 MiB NHWC
  u16*   VT  = Q;   // reuse Q region: Q dead after k_qk, VT written by k_vt after k_qk
  float* outp = (float*)d_out;

  k_prep<<<768, 256, 0, stream>>>(wo, wq, wk, wv, WT, WQKV);
  k_qkv<<<1024, 256, 0, stream>>>(x, WQKV, bq, bk, bv, Q, K, V);
  k_qk<<<dim3(64, 8), 256, 0, stream>>>(Q, K, ATT);
  k_vt<<<dim3(128, 8), 256, 0, stream>>>(V, VT);
  k_softmax<<<8192, 256, 0, stream>>>(ATT, P);
  k_pv<<<dim3(128, 8), 256, 0, stream>>>(P, VT, Yn);
  k_conv<<<dim3(512, 2), 256, 0, stream>>>(Yn, WT, bo, outp);
}